// Round 8
// baseline (173.427 us; speedup 1.0000x reference)
//
#include <hip/hip_runtime.h>
#include <hip/hip_bf16.h>

// Problem: x(4,256,64,64), offset(4,18,64,64), mask(4,9,64,64),
// weight(256,256,3,3) -> out(4,256,64,64). stride=1, pad=1, K=3.
// R8: both hot kernels are latency-bound -> raise concurrency WITHOUT
// replicating traffic (R7 lesson: splitting kk across blocks 4x'd HBM fetch).
//  - sample: 1024 blocks (64-row m-blocks x 4 oct-groups), all 9 kk per
//    thread (locality), kk-pairs with 16 gathers in flight before combine.
//  - gemm: LDS-free (R6 win), MT=64 NT=64, grid 1024, 4 blocks/CU.
//   A'[mb 0..127][kc 0..287][row 0..127] of 16B chunks (8 bf16)
//   B'[ob 0..3]  [kc 0..287][row 0..63]  of 16B chunks
#define BN 4
#define CN 256
#define HN 64
#define WN 64
#define ON 256
#define KKN 9
#define HWN 4096
#define KDIM 2304   // 9*256
#define MN 16384    // B*H*W
#define KC 288      // KDIM/8 chunks

using frag_ab = __attribute__((ext_vector_type(8))) short;  // 8 bf16
using frag_cd = __attribute__((ext_vector_type(4))) float;  // 4 fp32

static __device__ inline short f2bf(float f) {
    union { float f; unsigned u; } v; v.f = f;
    unsigned r = v.u + 0x7fffu + ((v.u >> 16) & 1u);
    return (short)(r >> 16);
}
static __device__ inline float bf2f(short s) {
    union { unsigned u; float f; } v; v.u = ((unsigned)(unsigned short)s) << 16;
    return v.f;
}

// ---------- kernel 1: prep = transpose x -> BHWC bf16 | repack weight ------
__global__ __launch_bounds__(256) void prep_kernel(const float* __restrict__ x,
                                                   const float* __restrict__ wsrc,
                                                   short* __restrict__ xb16,
                                                   short* __restrict__ wtb) {
    int bidx = blockIdx.x;
    int tid  = threadIdx.x;
    if (bidx < 1024) {
        __shared__ float tile[64][65];
        int b   = bidx >> 8;
        int rem = bidx & 255;
        int c0  = (rem >> 6) * 64;
        int p0  = (rem & 63) * 64;
        int tp = tid & 63, tc = tid >> 6;
        for (int i = 0; i < 16; ++i) {
            int c = tc + i * 4;
            tile[c][tp] = x[(b * CN + c0 + c) * HWN + p0 + tp];
        }
        __syncthreads();
        int tcc = tid & 63, tpp = tid >> 6;
        for (int i = 0; i < 16; ++i) {
            int p = tpp + i * 4;
            xb16[(b * HWN + p0 + p) * CN + c0 + tcc] = f2bf(tile[tcc][p]);
        }
    } else {
        int chunk = (bidx - 1024) * 256 + tid;   // < 4*288*64 = 73728
        int ob  = chunk / (KC * 64);
        int rem = chunk - ob * (KC * 64);
        int kc  = rem >> 6;
        int row = rem & 63;
        int o   = ob * 64 + row;
        int kk  = kc >> 5;
        int oct = kc & 31;
        frag_ab v;
        #pragma unroll
        for (int e = 0; e < 8; ++e)
            v[e] = f2bf(wsrc[(o * CN + oct * 8 + e) * 9 + kk]);
        *(frag_ab*)&wtb[(size_t)chunk * 8] = v;
    }
}

// ---------- kernel 2: sample -> A'[mb][kc][row] bf16 chunks ----------
// grid 1024: bid = mbb*4 + og; mbb: 64-row m-block (mb = mbb>>1, half=mbb&1),
// og: 8-oct group. thread: row64 = t&63, sub = t>>6 -> octs og*8+sub*2 (+0,+1).
// kk handled in pairs; all 16 corner gathers issued before combining.
__global__ __launch_bounds__(256) void sample_kernel(const short* __restrict__ xb16,
                                                     const float* __restrict__ offs,
                                                     const float* __restrict__ maskp,
                                                     short* __restrict__ A) {
    int bid  = blockIdx.x;
    int mbb  = bid >> 2;
    int og   = bid & 3;
    int t    = threadIdx.x;
    int row  = (mbb & 1) * 64 + (t & 63);
    int mb   = mbb >> 1;
    int sub  = t >> 6;
    int m = mb * 128 + row;
    int b = m >> 12;
    int h = (m >> 6) & 63;
    int w = m & 63;
    int oct0 = og * 8 + sub * 2;

    int off0[2][4];   // corner offsets into xb16 (element units), oct applied
    float cw[2][4];

#define SETUP(u, kk)                                                        \
    {                                                                       \
        const int ki = (kk) / 3, kj = (kk) % 3;                             \
        int obase = ((b * 18 + (kk) * 2) * 64 + h) * 64 + w;                \
        float dy = offs[obase];                                             \
        float dx = offs[obase + HWN];                                       \
        float mv = maskp[((b * 9 + (kk)) * 64 + h) * 64 + w];               \
        float py = (float)(h - 1 + ki) + dy;                                \
        float px = (float)(w - 1 + kj) + dx;                                \
        float y0f = floorf(py), x0f = floorf(px);                           \
        float wy = py - y0f, wx = px - x0f;                                 \
        int y0 = (int)y0f, x0 = (int)x0f;                                   \
        _Pragma("unroll")                                                   \
        for (int cy = 0; cy < 2; ++cy) {                                    \
            _Pragma("unroll")                                               \
            for (int cx = 0; cx < 2; ++cx) {                                \
                int yy = y0 + cy, xx = x0 + cx;                             \
                bool valid = (yy >= 0 && yy < HN && xx >= 0 && xx < WN);    \
                int yc = min(max(yy, 0), HN - 1);                           \
                int xc = min(max(xx, 0), WN - 1);                           \
                off0[u][cy * 2 + cx] =                                      \
                    ((b * HN + yc) * WN + xc) * CN + oct0 * 8;              \
                float wgt = (cy ? wy : 1.f - wy) * (cx ? wx : 1.f - wx) * mv;\
                cw[u][cy * 2 + cx] = valid ? wgt : 0.f;                     \
            }                                                               \
        }                                                                   \
    }

#define COMBINE_STORE(u, kk)                                                \
    {                                                                       \
        _Pragma("unroll")                                                   \
        for (int o = 0; o < 2; ++o) {                                       \
            frag_ab res;                                                    \
            _Pragma("unroll")                                               \
            for (int e = 0; e < 8; e += 2) {                                \
                float a0 = cw[u][0] * bf2f(v[u][0][o][e])                   \
                         + cw[u][1] * bf2f(v[u][1][o][e])                   \
                         + cw[u][2] * bf2f(v[u][2][o][e])                   \
                         + cw[u][3] * bf2f(v[u][3][o][e]);                  \
                float a1 = cw[u][0] * bf2f(v[u][0][o][e + 1])               \
                         + cw[u][1] * bf2f(v[u][1][o][e + 1])               \
                         + cw[u][2] * bf2f(v[u][2][o][e + 1])               \
                         + cw[u][3] * bf2f(v[u][3][o][e + 1]);              \
                __hip_bfloat162 p2 =                                        \
                    __float22bfloat162_rn(make_float2(a0, a1));             \
                res[e]     = *(short*)&p2.x;                                \
                res[e + 1] = *(short*)&p2.y;                                \
            }                                                               \
            int kc = (kk) * 32 + oct0 + o;                                  \
            *(frag_ab*)&A[(((size_t)mb * KC + kc) * 128 + row) * 8] = res;  \
        }                                                                   \
    }

    frag_ab v[2][4][2];
    #pragma unroll
    for (int kp = 0; kp < 4; ++kp) {
        int kk0 = kp * 2;
        SETUP(0, kk0)
        SETUP(1, kk0 + 1)
        #pragma unroll
        for (int u = 0; u < 2; ++u)
            #pragma unroll
            for (int c = 0; c < 4; ++c)
                #pragma unroll
                for (int o = 0; o < 2; ++o)
                    v[u][c][o] = *(const frag_ab*)&xb16[off0[u][c] + o * 8];
        COMBINE_STORE(0, kk0)
        COMBINE_STORE(1, kk0 + 1)
    }
    // tail kk = 8
    SETUP(0, 8)
    #pragma unroll
    for (int c = 0; c < 4; ++c)
        #pragma unroll
        for (int o = 0; o < 2; ++o)
            v[0][c][o] = *(const frag_ab*)&xb16[off0[0][c] + o * 8];
    COMBINE_STORE(0, 8)
#undef SETUP
#undef COMBINE_STORE
}

// ---------- kernel 3: LDS-free GEMM. MT=64, NT=64, grid 1024 ----------
// bid: mblk2 = bid&255 (64-row M block), oblk = bid>>8. Same-A blocks are
// bid+256k -> same XCD. K-step ks: af at A' chunk (ks*4+q)*128 +
// (mblk2&1)*64 + wv*16 + r; bf(j) at B' chunk (ks*4+q)*64 + j*16+r.
__global__ __launch_bounds__(256, 4) void gemm_kernel(const short* __restrict__ A,
                                                      const short* __restrict__ wtb,
                                                      float* __restrict__ out) {
    __shared__ float outb[64][65];   // epilogue transpose only
    int tid   = threadIdx.x;
    int bid   = blockIdx.x;
    int mblk2 = bid & 255;
    int oblk  = bid >> 8;
    int m0 = mblk2 * 64, o0 = oblk * 64;
    int wv = tid >> 6, lane = tid & 63;
    int q = lane >> 4, r = lane & 15;

    frag_cd acc[4];
    #pragma unroll
    for (int j = 0; j < 4; ++j)
        acc[j] = (frag_cd){0.f, 0.f, 0.f, 0.f};

    // lane-fixed bases (short units). ks strides: A 4096, B 2048.
    const short* ap = A + ((size_t)(mblk2 >> 1) * KC + q) * 1024
                        + ((mblk2 & 1) * 64 + wv * 16 + r) * 8;
    const short* bp = wtb + ((size_t)oblk * KC + q) * 512 + r * 8;

    frag_ab af0, af1, af2, bf0[4], bf1[4], bf2[4];

#define LOADK(AF, BF, ks)                                                  \
    {                                                                      \
        AF = *(const frag_ab*)(ap + (size_t)(ks) * 4096);                  \
        const short* b_ = bp + (size_t)(ks) * 2048;                        \
        BF[0] = *(const frag_ab*)(b_);                                     \
        BF[1] = *(const frag_ab*)(b_ + 128);                               \
        BF[2] = *(const frag_ab*)(b_ + 256);                               \
        BF[3] = *(const frag_ab*)(b_ + 384);                               \
    }

#define MFMAK(AF, BF)                                                      \
    {                                                                      \
        _Pragma("unroll")                                                  \
        for (int j = 0; j < 4; ++j)                                        \
            acc[j] = __builtin_amdgcn_mfma_f32_16x16x32_bf16(              \
                AF, BF[j], acc[j], 0, 0, 0);                               \
    }

    LOADK(af0, bf0, 0)
    LOADK(af1, bf1, 1)
    for (int kt = 0; kt < 23; ++kt) {
        int ks = kt * 3;
        LOADK(af2, bf2, ks + 2)
        MFMAK(af0, bf0)
        LOADK(af0, bf0, ks + 3)
        MFMAK(af1, bf1)
        LOADK(af1, bf1, ks + 4)
        MFMAK(af2, bf2)
    }
    LOADK(af2, bf2, 71)
    MFMAK(af0, bf0)
    MFMAK(af1, bf1)
    MFMAK(af2, bf2)

    // ---- epilogue: C-frag (row = q*4+reg, col = r) -> LDS -> BOHW ----
    #pragma unroll
    for (int j = 0; j < 4; ++j) {
        int ml = wv * 16 + q * 4;
        int ol = j * 16 + r;
        outb[ml + 0][ol] = acc[j][0];
        outb[ml + 1][ol] = acc[j][1];
        outb[ml + 2][ol] = acc[j][2];
        outb[ml + 3][ol] = acc[j][3];
    }
    __syncthreads();
    int b = m0 >> 12, h = (m0 >> 6) & 63;
    int w = tid & 63, sub = tid >> 6;
    #pragma unroll
    for (int oo = 0; oo < 16; ++oo) {
        int ol = sub * 16 + oo;
        out[(((size_t)b * ON + o0 + ol) * HN + h) * WN + w] = outb[w][ol];
    }
}

extern "C" void kernel_launch(void* const* d_in, const int* in_sizes, int n_in,
                              void* d_out, int out_size, void* d_ws, size_t ws_size,
                              hipStream_t stream) {
    const float* x      = (const float*)d_in[0];
    const float* offset = (const float*)d_in[1];
    const float* mask   = (const float*)d_in[2];
    const float* weight = (const float*)d_in[3];
    float* out = (float*)d_out;

    // ws: xb16 bf16 8 MiB | wtb bf16 1.125 MiB | A' bf16 72 MiB
    short* xb16 = (short*)d_ws;
    short* wtb  = (short*)((char*)d_ws + 8388608);
    short* A    = (short*)((char*)d_ws + 8388608 + 1179648);

    hipLaunchKernelGGL(prep_kernel,   dim3(1312), dim3(256), 0, stream,
                       x, weight, xb16, wtb);
    hipLaunchKernelGGL(sample_kernel, dim3(1024), dim3(256), 0, stream,
                       xb16, offset, mask, A);
    hipLaunchKernelGGL(gemm_kernel,   dim3(1024), dim3(256), 0, stream,
                       A, wtb, out);
}

// Round 9
// 149.705 us; speedup vs baseline: 1.1585x; 1.1585x over previous
//
#include <hip/hip_runtime.h>
#include <hip/hip_bf16.h>

// Problem: x(4,256,64,64), offset(4,18,64,64), mask(4,9,64,64),
// weight(256,256,3,3) -> out(4,256,64,64). stride=1, pad=1, K=3.
// R9: FUSED sample+GEMM (kills the 72MB A' HBM round-trip that bound R8).
//   prep:  x BCHW fp32 -> xb16 BHWC bf16 | weight -> B'[ob][kc][row] chunks
//   fused: grid 512, block = 32 m-rows x 256 o-cols, full K.
//     per kk: 256 thr bilinear-sample 32x256 A-tile -> LDS (ds_write_b128,
//     identity chunk order = conflict-free), barrier, 8 MFMA k-steps
//     (A: conflict-free ds_read_b128; B: direct global->VGPR, L2-resident),
//     barrier. Double-buffered A-tile. Direct stores, no atomics.
#define BN 4
#define CN 256
#define HN 64
#define WN 64
#define ON 256
#define KKN 9
#define HWN 4096
#define KDIM 2304   // 9*256
#define KC 288      // KDIM/8 chunks

using frag_ab = __attribute__((ext_vector_type(8))) short;  // 8 bf16
using frag_cd = __attribute__((ext_vector_type(4))) float;  // 4 fp32

static __device__ inline short f2bf(float f) {
    union { float f; unsigned u; } v; v.f = f;
    unsigned r = v.u + 0x7fffu + ((v.u >> 16) & 1u);
    return (short)(r >> 16);
}
static __device__ inline float bf2f(short s) {
    union { unsigned u; float f; } v; v.u = ((unsigned)(unsigned short)s) << 16;
    return v.f;
}

// ---------- kernel 1: prep = transpose x -> BHWC bf16 | repack weight ------
__global__ __launch_bounds__(256) void prep_kernel(const float* __restrict__ x,
                                                   const float* __restrict__ wsrc,
                                                   short* __restrict__ xb16,
                                                   short* __restrict__ wtb) {
    int bidx = blockIdx.x;
    int tid  = threadIdx.x;
    if (bidx < 1024) {
        __shared__ float tile[64][65];
        int b   = bidx >> 8;
        int rem = bidx & 255;
        int c0  = (rem >> 6) * 64;
        int p0  = (rem & 63) * 64;
        int tp = tid & 63, tc = tid >> 6;
        for (int i = 0; i < 16; ++i) {
            int c = tc + i * 4;
            tile[c][tp] = x[(b * CN + c0 + c) * HWN + p0 + tp];
        }
        __syncthreads();
        int tcc = tid & 63, tpp = tid >> 6;
        for (int i = 0; i < 16; ++i) {
            int p = tpp + i * 4;
            xb16[(b * HWN + p0 + p) * CN + c0 + tcc] = f2bf(tile[tcc][p]);
        }
    } else {
        int chunk = (bidx - 1024) * 256 + tid;   // < 4*288*64 = 73728
        int ob  = chunk / (KC * 64);
        int rem = chunk - ob * (KC * 64);
        int kc  = rem >> 6;
        int row = rem & 63;
        int o   = ob * 64 + row;
        int kk  = kc >> 5;
        int oct = kc & 31;
        frag_ab v;
        #pragma unroll
        for (int e = 0; e < 8; ++e)
            v[e] = f2bf(wsrc[(o * CN + oct * 8 + e) * 9 + kk]);
        *(frag_ab*)&wtb[(size_t)chunk * 8] = v;
    }
}

// ---------- kernel 2: fused sample + GEMM ----------
// block: 32 m-rows (m0 = bid*32) x 256 o-cols. 4 waves, wave wv owns cols
// [wv*64, wv*64+64). Sampling: thread t -> row = t&31, oct_lane = t>>5;
// pass p covers oct = p*8 + oct_lane; A-tile LDS chunk = oct*32+row = p*256+t
// (identity ds_write_b128). MFMA frag read: chunk (ks*4+q)*32 + i*16 + r.
__global__ __launch_bounds__(256, 2) void fused_kernel(const short* __restrict__ xb16,
                                                       const short* __restrict__ wtb,
                                                       const float* __restrict__ offs,
                                                       const float* __restrict__ maskp,
                                                       float* __restrict__ out) {
    __shared__ union {
        short Ab[2][8192];        // 2 x 16 KB A-tile (1024 chunks each)
        float outb[32 * 257];     // epilogue transpose, pad 257 (bank-clean)
    } sm;
    int tid = threadIdx.x;
    int m0  = blockIdx.x * 32;
    int b   = m0 >> 12;
    int h   = (m0 >> 6) & 63;
    int w0  = m0 & 63;            // 0 or 32
    int wv  = tid >> 6, lane = tid & 63;
    int q   = lane >> 4, r = lane & 15;
    int row = tid & 31;           // sampling row
    int ol8 = tid >> 5;           // oct_lane 0..7
    int wc  = w0 + row;           // width coord of this row's m

    frag_cd acc[2][4];
    #pragma unroll
    for (int i = 0; i < 2; ++i)
        #pragma unroll
        for (int j = 0; j < 4; ++j)
            acc[i][j] = (frag_cd){0.f, 0.f, 0.f, 0.f};

    for (int kk = 0; kk < KKN; ++kk) {
        short* dst = sm.Ab[kk & 1];
        // ---- sample phase: 32x256 A-tile for this kk ----
        {
            int ki = kk / 3, kj = kk - ki * 3;
            int obase = ((b * 18 + kk * 2) * 64 + h) * 64 + wc;
            float dy = offs[obase];
            float dx = offs[obase + HWN];
            float mv = maskp[((b * 9 + kk) * 64 + h) * 64 + wc];
            float py = (float)(h - 1 + ki) + dy;
            float px = (float)(wc - 1 + kj) + dx;
            float y0f = floorf(py), x0f = floorf(px);
            float wy = py - y0f, wx = px - x0f;
            int y0 = (int)y0f, x0 = (int)x0f;
            int   cb[4];
            float cw[4];
            #pragma unroll
            for (int cy = 0; cy < 2; ++cy)
                #pragma unroll
                for (int cx = 0; cx < 2; ++cx) {
                    int yy = y0 + cy, xx = x0 + cx;
                    bool valid = (yy >= 0 && yy < HN && xx >= 0 && xx < WN);
                    int yc = min(max(yy, 0), HN - 1);
                    int xc = min(max(xx, 0), WN - 1);
                    cb[cy * 2 + cx] = ((b * HN + yc) * WN + xc) * CN + ol8 * 8;
                    float wgt = (cy ? wy : 1.f - wy) * (cx ? wx : 1.f - wx) * mv;
                    cw[cy * 2 + cx] = valid ? wgt : 0.f;
                }
            // issue all 16 gathers (4 passes x 4 corners), then combine
            frag_ab v[4][4];
            #pragma unroll
            for (int p = 0; p < 4; ++p)
                #pragma unroll
                for (int c = 0; c < 4; ++c)
                    v[p][c] = *(const frag_ab*)&xb16[cb[c] + p * 64];
            #pragma unroll
            for (int p = 0; p < 4; ++p) {
                frag_ab res;
                #pragma unroll
                for (int e = 0; e < 8; e += 2) {
                    float a0 = cw[0] * bf2f(v[p][0][e]) + cw[1] * bf2f(v[p][1][e])
                             + cw[2] * bf2f(v[p][2][e]) + cw[3] * bf2f(v[p][3][e]);
                    float a1 = cw[0] * bf2f(v[p][0][e + 1]) + cw[1] * bf2f(v[p][1][e + 1])
                             + cw[2] * bf2f(v[p][2][e + 1]) + cw[3] * bf2f(v[p][3][e + 1]);
                    __hip_bfloat162 p2 = __float22bfloat162_rn(make_float2(a0, a1));
                    res[e]     = *(short*)&p2.x;
                    res[e + 1] = *(short*)&p2.y;
                }
                *(frag_ab*)&dst[(p * 256 + tid) * 8] = res;
            }
        }
        __syncthreads();
        // ---- MFMA phase: 8 k16-steps over this kk's 256 k ----
        #pragma unroll
        for (int ks = 0; ks < 8; ++ks) {
            frag_ab af[2], bf[4];
            #pragma unroll
            for (int i = 0; i < 2; ++i)
                af[i] = *(const frag_ab*)
                    &dst[(((ks * 4 + q) * 32) + i * 16 + r) * 8];
            #pragma unroll
            for (int j = 0; j < 4; ++j)
                bf[j] = *(const frag_ab*)
                    &wtb[(((size_t)wv * KC + kk * 32 + ks * 4 + q) * 64
                          + j * 16 + r) * 8];
            #pragma unroll
            for (int i = 0; i < 2; ++i)
                #pragma unroll
                for (int j = 0; j < 4; ++j)
                    acc[i][j] = __builtin_amdgcn_mfma_f32_16x16x32_bf16(
                        af[i], bf[j], acc[i][j], 0, 0, 0);
        }
        __syncthreads();
    }

    // ---- epilogue: acc (row=i*16+q*4+reg, col=wv*64+j*16+r) -> LDS -> BOHW
    #pragma unroll
    for (int i = 0; i < 2; ++i)
        #pragma unroll
        for (int j = 0; j < 4; ++j) {
            int ml = i * 16 + q * 4;
            int ol = wv * 64 + j * 16 + r;
            sm.outb[(ml + 0) * 257 + ol] = acc[i][j][0];
            sm.outb[(ml + 1) * 257 + ol] = acc[i][j][1];
            sm.outb[(ml + 2) * 257 + ol] = acc[i][j][2];
            sm.outb[(ml + 3) * 257 + ol] = acc[i][j][3];
        }
    __syncthreads();
    {
        int ww = tid & 31;        // width within tile
        int og = tid >> 5;        // 0..7
        #pragma unroll
        for (int oo = 0; oo < 32; ++oo) {
            int o = oo * 8 + og;
            out[(((size_t)b * ON + o) * HN + h) * WN + w0 + ww] =
                sm.outb[ww * 257 + o];
        }
    }
}

extern "C" void kernel_launch(void* const* d_in, const int* in_sizes, int n_in,
                              void* d_out, int out_size, void* d_ws, size_t ws_size,
                              hipStream_t stream) {
    const float* x      = (const float*)d_in[0];
    const float* offset = (const float*)d_in[1];
    const float* mask   = (const float*)d_in[2];
    const float* weight = (const float*)d_in[3];
    float* out = (float*)d_out;

    // ws: xb16 bf16 8 MiB | wtb (B') bf16 1.125 MiB
    short* xb16 = (short*)d_ws;
    short* wtb  = (short*)((char*)d_ws + 8388608);

    hipLaunchKernelGGL(prep_kernel,  dim3(1312), dim3(256), 0, stream,
                       x, weight, xb16, wtb);
    hipLaunchKernelGGL(fused_kernel, dim3(512),  dim3(256), 0, stream,
                       xb16, wtb, offset, mask, out);
}

// Round 10
// 138.145 us; speedup vs baseline: 1.2554x; 1.0837x over previous
//
#include <hip/hip_runtime.h>
#include <hip/hip_bf16.h>

// Problem: x(4,256,64,64), offset(4,18,64,64), mask(4,9,64,64),
// weight(256,256,3,3) -> out(4,256,64,64). stride=1, pad=1, K=3.
// R10: fused sample+GEMM with COALESCED corner-row gathers.
// R9 post-mortem: scattered per-lane gathers touched ~64 lines/inst ->
// L1 line-throughput bound. Now: wave-uniform (m,corner), lane=channel-quad
// -> one 512B corner row per load (8 lines). A-tile LDS uses oct-stride 33
// (padded) so ds_write_b64 scatter and ds_read_b128 frag reads are both
// uniformly bank-balanced. 1 barrier per kk (double-buffered A-tile).
#define BN 4
#define CN 256
#define HN 64
#define WN 64
#define ON 256
#define KKN 9
#define HWN 4096
#define KDIM 2304   // 9*256
#define KC 288      // KDIM/8 chunks

using frag_ab = __attribute__((ext_vector_type(8))) short;  // 8 bf16
using frag_cd = __attribute__((ext_vector_type(4))) float;  // 4 fp32
using short4v = __attribute__((ext_vector_type(4))) short;  // 4 bf16 (8B)

static __device__ inline short f2bf(float f) {
    union { float f; unsigned u; } v; v.f = f;
    unsigned r = v.u + 0x7fffu + ((v.u >> 16) & 1u);
    return (short)(r >> 16);
}
static __device__ inline float bf2f(short s) {
    union { unsigned u; float f; } v; v.u = ((unsigned)(unsigned short)s) << 16;
    return v.f;
}

// ---------- kernel 1: prep = transpose x -> BHWC bf16 | repack weight ------
__global__ __launch_bounds__(256) void prep_kernel(const float* __restrict__ x,
                                                   const float* __restrict__ wsrc,
                                                   short* __restrict__ xb16,
                                                   short* __restrict__ wtb) {
    int bidx = blockIdx.x;
    int tid  = threadIdx.x;
    if (bidx < 1024) {
        __shared__ float tile[64][65];
        int b   = bidx >> 8;
        int rem = bidx & 255;
        int c0  = (rem >> 6) * 64;
        int p0  = (rem & 63) * 64;
        int tp = tid & 63, tc = tid >> 6;
        for (int i = 0; i < 16; ++i) {
            int c = tc + i * 4;
            tile[c][tp] = x[(b * CN + c0 + c) * HWN + p0 + tp];
        }
        __syncthreads();
        int tcc = tid & 63, tpp = tid >> 6;
        for (int i = 0; i < 16; ++i) {
            int p = tpp + i * 4;
            xb16[(b * HWN + p0 + p) * CN + c0 + tcc] = f2bf(tile[tcc][p]);
        }
    } else {
        int chunk = (bidx - 1024) * 256 + tid;   // < 4*288*64 = 73728
        int ob  = chunk / (KC * 64);
        int rem = chunk - ob * (KC * 64);
        int kc  = rem >> 6;
        int row = rem & 63;
        int o   = ob * 64 + row;
        int kk  = kc >> 5;
        int oct = kc & 31;
        frag_ab v;
        #pragma unroll
        for (int e = 0; e < 8; ++e)
            v[e] = f2bf(wsrc[(o * CN + oct * 8 + e) * 9 + kk]);
        *(frag_ab*)&wtb[(size_t)chunk * 8] = v;
    }
}

// ---------- kernel 2: fused sample + GEMM ----------
// block: 32 m-rows (m0 = bid*32) x 256 o-cols, 4 waves (wave wv: cols
// wv*64..+64). Sampling: wave wv samples m-rows wv*8..wv*8+7; per m: 4
// corner rows, each read coalesced (lane = 4-channel group, 8B). A-tile LDS
// chunk position = 33*oct + m (16B chunks, padded stride -> bank-balanced).
// MFMA frag read (ks,q,i,r): chunk 33*(ks*4+q) + i*16 + r.
__global__ __launch_bounds__(256, 2) void fused_kernel(const short* __restrict__ xb16,
                                                       const short* __restrict__ wtb,
                                                       const float* __restrict__ offs,
                                                       const float* __restrict__ maskp,
                                                       float* __restrict__ out) {
    __shared__ union {
        short Ab[2][8448];        // 2 x 16.5 KB A-tile (1055 padded chunks)
        float outb[32 * 257];     // epilogue transpose, pad 257
    } sm;
    int tid = threadIdx.x;
    int m0  = blockIdx.x * 32;
    int b   = m0 >> 12;
    int h   = (m0 >> 6) & 63;
    int w0  = m0 & 63;            // 0 or 32
    int wv  = tid >> 6, lane = tid & 63;
    int q   = lane >> 4, r = lane & 15;
    // sampling write base (shorts): chunk 33*(lane>>1), half (lane&1)
    int wbase = 33 * (lane >> 1) * 8 + (lane & 1) * 4;

    frag_cd acc[2][4];
    #pragma unroll
    for (int i = 0; i < 2; ++i)
        #pragma unroll
        for (int j = 0; j < 4; ++j)
            acc[i][j] = (frag_cd){0.f, 0.f, 0.f, 0.f};

    for (int kk = 0; kk < KKN; ++kk) {
        short* dst = sm.Ab[kk & 1];
        int ki = kk / 3, kj = kk - ki * 3;
        // ---- sample phase: wave samples its 8 m-rows, coalesced rows ----
        #pragma unroll
        for (int i = 0; i < 8; ++i) {
            int mloc = wv * 8 + i;        // wave-uniform
            int wc   = w0 + mloc;
            int obase = ((b * 18 + kk * 2) * 64 + h) * 64 + wc;
            float dy = offs[obase];
            float dx = offs[obase + HWN];
            float mv = maskp[((b * 9 + kk) * 64 + h) * 64 + wc];
            float py = (float)(h - 1 + ki) + dy;
            float px = (float)(wc - 1 + kj) + dx;
            float y0f = floorf(py), x0f = floorf(px);
            float wy = py - y0f, wx = px - x0f;
            int y0 = (int)y0f, x0 = (int)x0f;
            int   cb[4];
            float cw[4];
            #pragma unroll
            for (int cy = 0; cy < 2; ++cy)
                #pragma unroll
                for (int cx = 0; cx < 2; ++cx) {
                    int yy = y0 + cy, xx = x0 + cx;
                    bool valid = (yy >= 0 && yy < HN && xx >= 0 && xx < WN);
                    int yc = min(max(yy, 0), HN - 1);
                    int xc = min(max(xx, 0), WN - 1);
                    cb[cy * 2 + cx] = ((b * HN + yc) * WN + xc) * CN;
                    float wgt = (cy ? wy : 1.f - wy) * (cx ? wx : 1.f - wx) * mv;
                    cw[cy * 2 + cx] = valid ? wgt : 0.f;
                }
            // 4 coalesced corner-row loads: lane covers channels 4*lane..+3
            short4v v[4];
            #pragma unroll
            for (int c = 0; c < 4; ++c)
                v[c] = *(const short4v*)&xb16[cb[c] + lane * 4];
            short4v res;
            #pragma unroll
            for (int e = 0; e < 4; e += 2) {
                float a0 = cw[0] * bf2f(v[0][e]) + cw[1] * bf2f(v[1][e])
                         + cw[2] * bf2f(v[2][e]) + cw[3] * bf2f(v[3][e]);
                float a1 = cw[0] * bf2f(v[0][e + 1]) + cw[1] * bf2f(v[1][e + 1])
                         + cw[2] * bf2f(v[2][e + 1]) + cw[3] * bf2f(v[3][e + 1]);
                __hip_bfloat162 p2 = __float22bfloat162_rn(make_float2(a0, a1));
                res[e]     = *(short*)&p2.x;
                res[e + 1] = *(short*)&p2.y;
            }
            *(short4v*)&dst[wbase + mloc * 8] = res;   // ds_write_b64
        }
        __syncthreads();
        // ---- MFMA phase: 8 k16-steps; A from LDS, B direct global (L2) ----
        #pragma unroll
        for (int ks = 0; ks < 8; ++ks) {
            frag_ab af[2], bf[4];
            #pragma unroll
            for (int i = 0; i < 2; ++i)
                af[i] = *(const frag_ab*)
                    &dst[(33 * (ks * 4 + q) + i * 16 + r) * 8];
            #pragma unroll
            for (int j = 0; j < 4; ++j)
                bf[j] = *(const frag_ab*)
                    &wtb[(((size_t)wv * KC + kk * 32 + ks * 4 + q) * 64
                          + j * 16 + r) * 8];
            #pragma unroll
            for (int i = 0; i < 2; ++i)
                #pragma unroll
                for (int j = 0; j < 4; ++j)
                    acc[i][j] = __builtin_amdgcn_mfma_f32_16x16x32_bf16(
                        af[i], bf[j], acc[i][j], 0, 0, 0);
        }
        // no trailing barrier: next kk writes the other buffer; the barrier
        // at kk+1 orders mfma(kk) before any sample(kk+2) buffer reuse.
    }
    __syncthreads();

    // ---- epilogue: acc (row=i*16+q*4+reg, col=wv*64+j*16+r) -> LDS -> BOHW
    #pragma unroll
    for (int i = 0; i < 2; ++i)
        #pragma unroll
        for (int j = 0; j < 4; ++j) {
            int ml = i * 16 + q * 4;
            int ol = wv * 64 + j * 16 + r;
            sm.outb[(ml + 0) * 257 + ol] = acc[i][j][0];
            sm.outb[(ml + 1) * 257 + ol] = acc[i][j][1];
            sm.outb[(ml + 2) * 257 + ol] = acc[i][j][2];
            sm.outb[(ml + 3) * 257 + ol] = acc[i][j][3];
        }
    __syncthreads();
    {
        int ww = tid & 31;        // width within tile
        int og = tid >> 5;        // 0..7
        #pragma unroll
        for (int oo = 0; oo < 32; ++oo) {
            int o = oo * 8 + og;
            out[(((size_t)b * ON + o) * HN + h) * WN + w0 + ww] =
                sm.outb[ww * 257 + o];
        }
    }
}

extern "C" void kernel_launch(void* const* d_in, const int* in_sizes, int n_in,
                              void* d_out, int out_size, void* d_ws, size_t ws_size,
                              hipStream_t stream) {
    const float* x      = (const float*)d_in[0];
    const float* offset = (const float*)d_in[1];
    const float* mask   = (const float*)d_in[2];
    const float* weight = (const float*)d_in[3];
    float* out = (float*)d_out;

    // ws: xb16 bf16 8 MiB | wtb (B') bf16 1.125 MiB
    short* xb16 = (short*)d_ws;
    short* wtb  = (short*)((char*)d_ws + 8388608);

    hipLaunchKernelGGL(prep_kernel,  dim3(1312), dim3(256), 0, stream,
                       x, weight, xb16, wtb);
    hipLaunchKernelGGL(fused_kernel, dim3(512),  dim3(256), 0, stream,
                       xb16, wtb, offset, mask, out);
}